// Round 8
// baseline (306.629 us; speedup 1.0000x reference)
//
#include <hip/hip_runtime.h>
#include <math.h>

#define NEG_INF -1000000000.0f

// ---------------------------------------------------------------------------
// Precompute kernel: blocks 0..63 -> posc (j-quad interleaved) ; blocks
// 64..191 -> tgtc[b][j] = target_emb[b] @ w_tgt.
// posc layout: posc[jq][s][4] (jq=j>>2) so the main kernel's per-lane (s)
// acc-init float4 loads are fully coalesced (16 B/lane, contiguous 1 KiB).
// ---------------------------------------------------------------------------
__global__ __launch_bounds__(64) void doe_pre_kernel(
    const float* __restrict__ pos_w1, const float* __restrict__ pos_b1,
    const float* __restrict__ pos_w2, const float* __restrict__ pos_b2,
    const float* __restrict__ att_w1, const float* __restrict__ att_b1,
    const float* __restrict__ target_emb,
    float* __restrict__ posc, float* __restrict__ tgtc)
{
    const int tid = threadIdx.x;
    if (blockIdx.x < 64) {
        const int s = blockIdx.x;
        __shared__ float p1[64];
        __shared__ float pe[64];
        float pos = (float)s * (1.0f / 63.0f);
        p1[tid] = fmaxf(fmaf(pos, pos_w1[tid], pos_b1[tid]), 0.0f);
        __syncthreads();
        float acc = pos_b2[tid];
        #pragma unroll
        for (int h = 0; h < 64; ++h) acc = fmaf(p1[h], pos_w2[h * 64 + tid], acc);
        pe[tid] = acc;
        __syncthreads();
        float pc = att_b1[tid];
        #pragma unroll
        for (int h = 0; h < 64; ++h) pc = fmaf(pe[h], att_w1[(64 + h) * 64 + tid], pc);
        posc[(tid >> 2) * 256 + s * 4 + (tid & 3)] = pc;   // [jq][s][4]
    } else {
        const int b = blockIdx.x - 64;
        const float* trow = target_emb + b * 64;   // wave-uniform -> s_load
        float acc = 0.0f;
        #pragma unroll
        for (int d = 0; d < 64; ++d) acc = fmaf(trow[d], att_w1[(128 + d) * 64 + tid], acc);
        tgtc[b * 64 + tid] = acc;
    }
}

// ---------------------------------------------------------------------------
// Main fused kernel, v3: zero LDS/barriers; j-dimension split into two
// sequential halves (acc[32]) to cut register pressure.
// R6 evidence: v2 (acc[64]) compiled to 64 arch VGPR + AGPR parking + 8 MB
// scratch spill -> 4 waves/SIMD, VALUBusy 44%, dur 103 us (latency-bound).
// acc[32] targets ~80 total VGPR -> 6 waves/SIMD; row re-read for half 2 is
// L2/L3-hot and prefetch-covered. Accumulation order identical to v2.
// ---------------------------------------------------------------------------
__device__ __forceinline__ void fma4rows32(float acc[32], const float4 a,
                                           const float* __restrict__ w0)
{
    #pragma unroll
    for (int j = 0; j < 32; ++j) {
        float t0 = fmaf(a.w, w0[192 + j], acc[j]);
        t0 = fmaf(a.z, w0[128 + j], t0);
        t0 = fmaf(a.y, w0[64 + j], t0);
        acc[j] = fmaf(a.x, w0[j], t0);
    }
}

__global__ __launch_bounds__(256, 6) void doe_main_kernel(
    const float* __restrict__ seg_emb, const int* __restrict__ smask,
    const float* __restrict__ att_w1, const float* __restrict__ att_w2,
    const float* __restrict__ att_b2, const float* __restrict__ proj_w,
    const float* __restrict__ proj_b, const float* __restrict__ ln_g,
    const float* __restrict__ ln_b, const float* __restrict__ posc,
    const float* __restrict__ tgtc, float* __restrict__ out)
{
    const int w    = threadIdx.x >> 6;
    const int lane = threadIdx.x & 63;
    const int g    = (blockIdx.x << 2) | w;   // tile id = b*64 + t
    const int b    = g >> 6;
    const int s    = lane;

    const float4* rp4 = (const float4*)(seg_emb + (size_t)g * 4096 + s * 64);

    // ---- mask early: latency hides under the GEMM phase ----
    const int mval = smask[(g << 6) | s];

    float sc = att_b2[0];

    #pragma unroll 1
    for (int h = 0; h < 2; ++h) {
        const int jbase = h << 5;

        // ---- acc init: coalesced posc quads + wave-uniform tgtc s_loads ----
        float acc[32];
        {
            const float4* pq = (const float4*)posc + (h * 8) * 64 + s;
            const float*  tr = tgtc + b * 64 + jbase;
            #pragma unroll
            for (int jq = 0; jq < 8; ++jq) {
                float4 pv = pq[jq * 64];
                acc[4 * jq + 0] = pv.x + tr[4 * jq + 0];
                acc[4 * jq + 1] = pv.y + tr[4 * jq + 1];
                acc[4 * jq + 2] = pv.z + tr[4 * jq + 2];
                acc[4 * jq + 3] = pv.w + tr[4 * jq + 3];
            }
        }

        // ---- GEMM half: 16 d-chunks, groups of 4, register prefetch ----
        float4 c0 = rp4[0], c1 = rp4[1], c2 = rp4[2], c3 = rp4[3];
        #pragma unroll 1
        for (int dq = 0; dq < 3; ++dq) {
            float4 n0 = rp4[4 * dq + 4], n1 = rp4[4 * dq + 5];
            float4 n2 = rp4[4 * dq + 6], n3 = rp4[4 * dq + 7];
            const float* wq = att_w1 + dq * 1024 + jbase;  // uniform -> s_load
            fma4rows32(acc, c0, wq);
            fma4rows32(acc, c1, wq + 256);
            fma4rows32(acc, c2, wq + 512);
            fma4rows32(acc, c3, wq + 768);
            c0 = n0; c1 = n1; c2 = n2; c3 = n3;
        }
        {   // epilogue dq = 3
            const float* wq = att_w1 + 3072 + jbase;
            fma4rows32(acc, c0, wq);
            fma4rows32(acc, c1, wq + 256);
            fma4rows32(acc, c2, wq + 512);
            fma4rows32(acc, c3, wq + 768);
        }

        // ---- partial score over this j-half ----
        const float* w2 = att_w2 + jbase;     // uniform -> s_load
        #pragma unroll
        for (int j = 0; j < 32; ++j) sc = fmaf(fmaxf(acc[j], 0.0f), w2[j], sc);
    }

    if (mval == 0) sc = NEG_INF;

    // ---- wave softmax (all-masked row -> uniform 1/64, matches jax) ----
    float mx = sc;
    #pragma unroll
    for (int off = 32; off; off >>= 1) mx = fmaxf(mx, __shfl_xor(mx, off));
    float e = __expf(sc - mx);
    float sum = e;
    #pragma unroll
    for (int off = 32; off; off >>= 1) sum += __shfl_xor(sum, off);
    const float p = e / sum;                  // attn weight for row s=lane

    // ---- weighted sum over s: coalesced column re-reads (cache-hot) ----
    const float* colb = seg_emb + (size_t)g * 4096 + lane;   // d = lane
    float segv = 0.0f;
    #pragma unroll
    for (int s2 = 0; s2 < 64; ++s2) {
        float av = __shfl(p, s2);             // broadcast attn[s2]
        segv = fmaf(av, colb[s2 * 64], segv);
    }

    // ---- projection: segv broadcast + coalesced proj_w rows ----
    float o = proj_b[lane];
    #pragma unroll
    for (int d2 = 0; d2 < 64; ++d2) {
        float sv = __shfl(segv, d2);
        o = fmaf(sv, proj_w[d2 * 64 + lane], o);
    }

    // ---- layernorm ----
    float ssum = o;
    #pragma unroll
    for (int off = 32; off; off >>= 1) ssum += __shfl_xor(ssum, off);
    float mu = ssum * (1.0f / 64.0f);
    float df = o - mu;
    float vsum = df * df;
    #pragma unroll
    for (int off = 32; off; off >>= 1) vsum += __shfl_xor(vsum, off);
    float var = vsum * (1.0f / 64.0f);
    float inv = 1.0f / sqrtf(var + 1e-5f);
    out[(g << 6) | lane] = fmaf(df * inv, ln_g[lane], ln_b[lane]);
}

extern "C" void kernel_launch(void* const* d_in, const int* in_sizes, int n_in,
                              void* d_out, int out_size, void* d_ws, size_t ws_size,
                              hipStream_t stream)
{
    const float* seg_emb    = (const float*)d_in[0];
    const int*   smask      = (const int*)  d_in[1];
    const float* target_emb = (const float*)d_in[2];
    const float* pos_w1     = (const float*)d_in[3];
    const float* pos_b1     = (const float*)d_in[4];
    const float* pos_w2     = (const float*)d_in[5];
    const float* pos_b2     = (const float*)d_in[6];
    const float* att_w1     = (const float*)d_in[7];
    const float* att_b1     = (const float*)d_in[8];
    const float* att_w2     = (const float*)d_in[9];
    const float* att_b2     = (const float*)d_in[10];
    const float* proj_w     = (const float*)d_in[11];
    const float* proj_b     = (const float*)d_in[12];
    const float* ln_g       = (const float*)d_in[13];
    const float* ln_b       = (const float*)d_in[14];
    float* out = (float*)d_out;

    float* posc = (float*)d_ws;        // 4096 floats, [jq][s][4] layout
    float* tgtc = posc + 4096;         // 8192 floats

    doe_pre_kernel<<<192, 64, 0, stream>>>(pos_w1, pos_b1, pos_w2, pos_b2,
                                           att_w1, att_b1, target_emb, posc, tgtc);
    doe_main_kernel<<<2048, 256, 0, stream>>>(seg_emb, smask, att_w1, att_w2,
                                              att_b2, proj_w, proj_b, ln_g, ln_b,
                                              posc, tgtc, out);
}

// Round 9
// 277.460 us; speedup vs baseline: 1.1051x; 1.1051x over previous
//
#include <hip/hip_runtime.h>
#include <math.h>

#define NEG_INF -1000000000.0f

// ---------------------------------------------------------------------------
// Precompute kernel: blocks 0..63 -> posc (j-quad interleaved) ; blocks
// 64..191 -> tgtc[b][j] = target_emb[b] @ w_tgt.
// posc layout: posc[jq][s][4] (jq=j>>2) so the main kernel's per-lane (s)
// acc-init float4 loads are fully coalesced (16 B/lane, contiguous 1 KiB).
// ---------------------------------------------------------------------------
__global__ __launch_bounds__(64) void doe_pre_kernel(
    const float* __restrict__ pos_w1, const float* __restrict__ pos_b1,
    const float* __restrict__ pos_w2, const float* __restrict__ pos_b2,
    const float* __restrict__ att_w1, const float* __restrict__ att_b1,
    const float* __restrict__ target_emb,
    float* __restrict__ posc, float* __restrict__ tgtc)
{
    const int tid = threadIdx.x;
    if (blockIdx.x < 64) {
        const int s = blockIdx.x;
        __shared__ float p1[64];
        __shared__ float pe[64];
        float pos = (float)s * (1.0f / 63.0f);
        p1[tid] = fmaxf(fmaf(pos, pos_w1[tid], pos_b1[tid]), 0.0f);
        __syncthreads();
        float acc = pos_b2[tid];
        #pragma unroll
        for (int h = 0; h < 64; ++h) acc = fmaf(p1[h], pos_w2[h * 64 + tid], acc);
        pe[tid] = acc;
        __syncthreads();
        float pc = att_b1[tid];
        #pragma unroll
        for (int h = 0; h < 64; ++h) pc = fmaf(pe[h], att_w1[(64 + h) * 64 + tid], pc);
        posc[(tid >> 2) * 256 + s * 4 + (tid & 3)] = pc;   // [jq][s][4]
    } else {
        const int b = blockIdx.x - 64;
        const float* trow = target_emb + b * 64;   // wave-uniform -> s_load
        float acc = 0.0f;
        #pragma unroll
        for (int d = 0; d < 64; ++d) acc = fmaf(trow[d], att_w1[(128 + d) * 64 + tid], acc);
        tgtc[b * 64 + tid] = acc;
    }
}

// ---------------------------------------------------------------------------
// Main fused kernel, v4: zero LDS/barriers; acc[32] j-halves.
// R8 post-mortem: v3's __launch_bounds__(256,6) forced 40 VGPR -> massive
// scratch spill (WRITE 51MB, FETCH 367MB) -> dur 144us. Live set needs ~75
// regs. v4: (256,5) -> ~96-reg budget, no spill, 5 waves/EU; prefetch depth
// halved (2 float4); 4-way partial accumulators break the 64-deep dependent
// chains in score / weighted-sum / proj (shfl+L2-load latency was serial).
// ---------------------------------------------------------------------------
__device__ __forceinline__ void fma4rows32(float acc[32], const float4 a,
                                           const float* __restrict__ w0)
{
    #pragma unroll
    for (int j = 0; j < 32; ++j) {
        float t0 = fmaf(a.w, w0[192 + j], acc[j]);
        t0 = fmaf(a.z, w0[128 + j], t0);
        t0 = fmaf(a.y, w0[64 + j], t0);
        acc[j] = fmaf(a.x, w0[j], t0);
    }
}

__global__ __launch_bounds__(256, 5) void doe_main_kernel(
    const float* __restrict__ seg_emb, const int* __restrict__ smask,
    const float* __restrict__ att_w1, const float* __restrict__ att_w2,
    const float* __restrict__ att_b2, const float* __restrict__ proj_w,
    const float* __restrict__ proj_b, const float* __restrict__ ln_g,
    const float* __restrict__ ln_b, const float* __restrict__ posc,
    const float* __restrict__ tgtc, float* __restrict__ out)
{
    const int w    = threadIdx.x >> 6;
    const int lane = threadIdx.x & 63;
    const int g    = (blockIdx.x << 2) | w;   // tile id = b*64 + t
    const int b    = g >> 6;
    const int s    = lane;

    const float4* rp4 = (const float4*)(seg_emb + (size_t)g * 4096 + s * 64);

    // ---- mask early: latency hides under the GEMM phase ----
    const int mval = smask[(g << 6) | s];

    float sc = att_b2[0];

    #pragma unroll 1
    for (int h = 0; h < 2; ++h) {
        const int jbase = h << 5;

        // ---- acc init: coalesced posc quads + wave-uniform tgtc s_loads ----
        float acc[32];
        {
            const float4* pq = (const float4*)posc + (h * 8) * 64 + s;
            const float*  tr = tgtc + b * 64 + jbase;
            #pragma unroll
            for (int jq = 0; jq < 8; ++jq) {
                float4 pv = pq[jq * 64];
                acc[4 * jq + 0] = pv.x + tr[4 * jq + 0];
                acc[4 * jq + 1] = pv.y + tr[4 * jq + 1];
                acc[4 * jq + 2] = pv.z + tr[4 * jq + 2];
                acc[4 * jq + 3] = pv.w + tr[4 * jq + 3];
            }
        }

        // ---- GEMM half: 16 d-chunks, groups of 2, depth-1 prefetch ----
        float4 c0 = rp4[0], c1 = rp4[1];
        #pragma unroll 1
        for (int dq = 0; dq < 7; ++dq) {
            float4 n0 = rp4[2 * dq + 2], n1 = rp4[2 * dq + 3];
            const float* wq = att_w1 + dq * 512 + jbase;   // uniform -> s_load
            fma4rows32(acc, c0, wq);
            fma4rows32(acc, c1, wq + 256);
            c0 = n0; c1 = n1;
        }
        {   // epilogue dq = 7
            const float* wq = att_w1 + 3584 + jbase;
            fma4rows32(acc, c0, wq);
            fma4rows32(acc, c1, wq + 256);
        }

        // ---- partial score over this j-half (4-way partials) ----
        const float* w2 = att_w2 + jbase;     // uniform -> s_load
        float s0 = 0.0f, s1 = 0.0f, s2 = 0.0f, s3 = 0.0f;
        #pragma unroll
        for (int jq = 0; jq < 8; ++jq) {
            s0 = fmaf(fmaxf(acc[4 * jq + 0], 0.0f), w2[4 * jq + 0], s0);
            s1 = fmaf(fmaxf(acc[4 * jq + 1], 0.0f), w2[4 * jq + 1], s1);
            s2 = fmaf(fmaxf(acc[4 * jq + 2], 0.0f), w2[4 * jq + 2], s2);
            s3 = fmaf(fmaxf(acc[4 * jq + 3], 0.0f), w2[4 * jq + 3], s3);
        }
        sc += (s0 + s1) + (s2 + s3);
    }

    if (mval == 0) sc = NEG_INF;

    // ---- wave softmax (all-masked row -> uniform 1/64, matches jax) ----
    float mx = sc;
    #pragma unroll
    for (int off = 32; off; off >>= 1) mx = fmaxf(mx, __shfl_xor(mx, off));
    float e = __expf(sc - mx);
    float sum = e;
    #pragma unroll
    for (int off = 32; off; off >>= 1) sum += __shfl_xor(sum, off);
    const float p = e / sum;                  // attn weight for row s=lane

    // ---- weighted sum over s: coalesced column re-reads, 4 partials ----
    const float* colb = seg_emb + (size_t)g * 4096 + lane;   // d = lane
    float v0 = 0.0f, v1 = 0.0f, v2 = 0.0f, v3 = 0.0f;
    #pragma unroll
    for (int sq = 0; sq < 16; ++sq) {
        v0 = fmaf(__shfl(p, 4 * sq + 0), colb[(4 * sq + 0) * 64], v0);
        v1 = fmaf(__shfl(p, 4 * sq + 1), colb[(4 * sq + 1) * 64], v1);
        v2 = fmaf(__shfl(p, 4 * sq + 2), colb[(4 * sq + 2) * 64], v2);
        v3 = fmaf(__shfl(p, 4 * sq + 3), colb[(4 * sq + 3) * 64], v3);
    }
    const float segv = (v0 + v1) + (v2 + v3);

    // ---- projection: segv broadcast + coalesced proj_w rows, 4 partials ----
    const float* pw = proj_w + lane;
    float o0 = proj_b[lane], o1 = 0.0f, o2 = 0.0f, o3 = 0.0f;
    #pragma unroll
    for (int dq = 0; dq < 16; ++dq) {
        o0 = fmaf(__shfl(segv, 4 * dq + 0), pw[(4 * dq + 0) * 64], o0);
        o1 = fmaf(__shfl(segv, 4 * dq + 1), pw[(4 * dq + 1) * 64], o1);
        o2 = fmaf(__shfl(segv, 4 * dq + 2), pw[(4 * dq + 2) * 64], o2);
        o3 = fmaf(__shfl(segv, 4 * dq + 3), pw[(4 * dq + 3) * 64], o3);
    }
    const float o = (o0 + o1) + (o2 + o3);

    // ---- layernorm ----
    float ssum = o;
    #pragma unroll
    for (int off = 32; off; off >>= 1) ssum += __shfl_xor(ssum, off);
    float mu = ssum * (1.0f / 64.0f);
    float df = o - mu;
    float vsum = df * df;
    #pragma unroll
    for (int off = 32; off; off >>= 1) vsum += __shfl_xor(vsum, off);
    float var = vsum * (1.0f / 64.0f);
    float inv = 1.0f / sqrtf(var + 1e-5f);
    out[(g << 6) | lane] = fmaf(df * inv, ln_g[lane], ln_b[lane]);
}

extern "C" void kernel_launch(void* const* d_in, const int* in_sizes, int n_in,
                              void* d_out, int out_size, void* d_ws, size_t ws_size,
                              hipStream_t stream)
{
    const float* seg_emb    = (const float*)d_in[0];
    const int*   smask      = (const int*)  d_in[1];
    const float* target_emb = (const float*)d_in[2];
    const float* pos_w1     = (const float*)d_in[3];
    const float* pos_b1     = (const float*)d_in[4];
    const float* pos_w2     = (const float*)d_in[5];
    const float* pos_b2     = (const float*)d_in[6];
    const float* att_w1     = (const float*)d_in[7];
    const float* att_b1     = (const float*)d_in[8];
    const float* att_w2     = (const float*)d_in[9];
    const float* att_b2     = (const float*)d_in[10];
    const float* proj_w     = (const float*)d_in[11];
    const float* proj_b     = (const float*)d_in[12];
    const float* ln_g       = (const float*)d_in[13];
    const float* ln_b       = (const float*)d_in[14];
    float* out = (float*)d_out;

    float* posc = (float*)d_ws;        // 4096 floats, [jq][s][4] layout
    float* tgtc = posc + 4096;         // 8192 floats

    doe_pre_kernel<<<192, 64, 0, stream>>>(pos_w1, pos_b1, pos_w2, pos_b2,
                                           att_w1, att_b1, target_emb, posc, tgtc);
    doe_main_kernel<<<2048, 256, 0, stream>>>(seg_emb, smask, att_w1, att_w2,
                                              att_b2, proj_w, proj_b, ln_g, ln_b,
                                              posc, tgtc, out);
}